// Round 1
// baseline (2213.733 us; speedup 1.0000x reference)
//
#include <hip/hip_runtime.h>
#include <hip/hip_bf16.h>
#include <cstdint>
#include <cstddef>

// Problem constants
static constexpr int N_TOK = 49152;     // B*M = 8192*6
static constexpr int NE    = 5;         // experts
// d_out offsets (floats), outputs concatenated in reference return order
static constexpr size_t OFF_TRAJ     = 0;          // [N,120]
static constexpr size_t OFF_SCORE    = 5898240;    // [N]
static constexpr size_t OFF_LOGITS   = 5947392;    // [N,5]
static constexpr size_t OFF_IDX      = 6193152;    // [N,2]  (ints stored as floats)
static constexpr size_t OFF_AUX      = 6291456;    // [1]
static constexpr size_t OFF_TRAJALL  = 6291457;    // [5,N,120]
static constexpr size_t OFF_SCOREALL = 35782657;   // [5,N]

__device__ __forceinline__ float gelu_f(float x) {
    return 0.5f * x * (1.0f + erff(x * 0.70710678118654752440f));
}

// ---------------------------------------------------------------------------
// Generic fused GEMM + bias + (gelu) + scale:  C[N,H] = act(A[N,K] @ W[K,H] + b) * alpha
// Tile: 128 rows x 128 cols, 256 threads, 8x8 per thread, K chunk = 16.
// A dtype: fp32 or bf16 (template). Out dtype: fp32 or bf16 (template).
// N is always a multiple of 128; K a multiple of 16; H arbitrary (guarded).
// ---------------------------------------------------------------------------
template<bool ABF16, bool OUTBF16, bool GELU>
__global__ __launch_bounds__(256)
void mlp_gemm(const void* __restrict__ Ap, const float* __restrict__ W,
              const float* __restrict__ bias, void* __restrict__ Cp,
              int Kd, int H, float alpha)
{
    __shared__ float As[16][128];   // [k][m]
    __shared__ float Ws[16][128];   // [k][n]

    const int tid  = threadIdx.x;
    const int tx   = tid & 15;      // col group (8 cols)
    const int ty   = tid >> 4;      // row group (8 rows)
    const int row0 = blockIdx.x * 128;
    const int col0 = blockIdx.y * 128;

    // A staging: each thread loads 8 consecutive k at one row
    const int lm = tid >> 1;          // 0..127
    const int lk = (tid & 1) * 8;     // 0 or 8

    float acc[8][8] = {};

    for (int k0 = 0; k0 < Kd; k0 += 16) {
        // ---- stage A tile ----
        if (ABF16) {
            const uint16_t* A = (const uint16_t*)Ap;
            const uint16_t* src = A + (size_t)(row0 + lm) * Kd + k0 + lk;
            uint4 v = *(const uint4*)src;           // 8 bf16 = 16B, aligned
            const uint16_t* s = (const uint16_t*)&v;
            #pragma unroll
            for (int j = 0; j < 8; ++j)
                As[lk + j][lm] = __uint_as_float(((uint32_t)s[j]) << 16);
        } else {
            const float* A = (const float*)Ap;
            const float* src = A + (size_t)(row0 + lm) * Kd + k0 + lk;
            float4 f0 = *(const float4*)src;
            float4 f1 = *(const float4*)(src + 4);
            As[lk + 0][lm] = f0.x; As[lk + 1][lm] = f0.y;
            As[lk + 2][lm] = f0.z; As[lk + 3][lm] = f0.w;
            As[lk + 4][lm] = f1.x; As[lk + 5][lm] = f1.y;
            As[lk + 6][lm] = f1.z; As[lk + 7][lm] = f1.w;
        }
        // ---- stage W tile: row k0+ty, cols col0+tx*8..+7 ----
        {
            const int wc = col0 + tx * 8;
            if (wc + 8 <= H) {
                const float* src = W + (size_t)(k0 + ty) * H + wc;
                float4 f0 = *(const float4*)src;
                float4 f1 = *(const float4*)(src + 4);
                *(float4*)&Ws[ty][tx * 8]     = f0;
                *(float4*)&Ws[ty][tx * 8 + 4] = f1;
            } else {
                #pragma unroll
                for (int j = 0; j < 8; ++j) {
                    int c = wc + j;
                    Ws[ty][tx * 8 + j] = (c < H) ? W[(size_t)(k0 + ty) * H + c] : 0.0f;
                }
            }
        }
        __syncthreads();
        #pragma unroll
        for (int kk = 0; kk < 16; ++kk) {
            float a[8], w[8];
            *(float4*)&a[0] = *(const float4*)&As[kk][ty * 8];
            *(float4*)&a[4] = *(const float4*)&As[kk][ty * 8 + 4];
            *(float4*)&w[0] = *(const float4*)&Ws[kk][tx * 8];
            *(float4*)&w[4] = *(const float4*)&Ws[kk][tx * 8 + 4];
            #pragma unroll
            for (int i = 0; i < 8; ++i)
                #pragma unroll
                for (int j = 0; j < 8; ++j)
                    acc[i][j] = fmaf(a[i], w[j], acc[i][j]);
        }
        __syncthreads();
    }

    // ---- epilogue ----
    #pragma unroll
    for (int i = 0; i < 8; ++i) {
        const int r = row0 + ty * 8 + i;
        #pragma unroll
        for (int j = 0; j < 8; ++j) {
            const int c = col0 + tx * 8 + j;
            if (c < H) {
                float v = acc[i][j] + bias[c];
                if (GELU) v = gelu_f(v);
                v *= alpha;
                if (OUTBF16) {
                    ((__hip_bfloat16*)Cp)[(size_t)r * H + c] = __float2bfloat16(v);
                } else {
                    ((float*)Cp)[(size_t)r * H + c] = v;
                }
            }
        }
    }
}

// ---------------------------------------------------------------------------
// Router post-process: softmax (for aux partial sums), top-2, top-2 softmax.
// One thread per token; 192 blocks x 256 threads = 49152.
// ---------------------------------------------------------------------------
__global__ __launch_bounds__(256)
void router_post(const float* __restrict__ logits, float* __restrict__ oidx,
                 float* __restrict__ tp, int* __restrict__ ti,
                 float* __restrict__ part)
{
    const int tid = threadIdx.x;
    const int n = blockIdx.x * 256 + tid;

    float l[5];
    #pragma unroll
    for (int e = 0; e < 5; ++e) l[e] = logits[(size_t)n * 5 + e];

    // full softmax (only needed for aux loss average)
    float m = l[0];
    #pragma unroll
    for (int e = 1; e < 5; ++e) m = fmaxf(m, l[e]);
    float p[5], s = 0.f;
    #pragma unroll
    for (int e = 0; e < 5; ++e) { p[e] = expf(l[e] - m); s += p[e]; }
    const float inv = 1.0f / s;

    __shared__ float red[256];
    #pragma unroll
    for (int e = 0; e < 5; ++e) {
        red[tid] = p[e] * inv;
        __syncthreads();
        for (int off = 128; off > 0; off >>= 1) {
            if (tid < off) red[tid] += red[tid + off];
            __syncthreads();
        }
        if (tid == 0) part[blockIdx.x * 5 + e] = red[0];
        __syncthreads();
    }

    // top-2 (stable: ties keep the lower index, matching jax.lax.top_k)
    int i0 = 0; float v0 = l[0];
    #pragma unroll
    for (int e = 1; e < 5; ++e) if (l[e] > v0) { v0 = l[e]; i0 = e; }
    int i1 = -1; float v1 = -1e30f;
    #pragma unroll
    for (int e = 0; e < 5; ++e) if (e != i0 && l[e] > v1) { v1 = l[e]; i1 = e; }

    const float t  = expf(v1 - v0);
    const float q0 = 1.0f / (1.0f + t);
    const float q1 = t / (1.0f + t);

    oidx[(size_t)n * 2]     = (float)i0;
    oidx[(size_t)n * 2 + 1] = (float)i1;
    tp[n * 2] = q0; tp[n * 2 + 1] = q1;
    ti[n * 2] = i0; ti[n * 2 + 1] = i1;
}

// ---------------------------------------------------------------------------
// Combine: final_traj = 0.3*shared (already in ftraj) + 0.7*sum_k p_k*traj_all[i_k]
// One thread per (token, traj-element). q==0 thread also does the score.
// ---------------------------------------------------------------------------
__global__ __launch_bounds__(256)
void combine_kernel(const float* __restrict__ trajall, const float* __restrict__ scoreall,
                    const float* __restrict__ tp, const int* __restrict__ ti,
                    float* __restrict__ ftraj, float* __restrict__ fscore)
{
    const size_t i = (size_t)blockIdx.x * 256 + threadIdx.x;   // < N*120
    const int n = (int)(i / 120);
    const int q = (int)(i - (size_t)n * 120);
    const int i0 = ti[n * 2], i1 = ti[n * 2 + 1];
    const float p0 = tp[n * 2], p1 = tp[n * 2 + 1];

    const float a = trajall[((size_t)i0 * N_TOK + n) * 120 + q];
    const float b = trajall[((size_t)i1 * N_TOK + n) * 120 + q];
    ftraj[i] = ftraj[i] + 0.7f * (p0 * a + p1 * b);

    if (q == 0) {
        const float sa = scoreall[(size_t)i0 * N_TOK + n];
        const float sb = scoreall[(size_t)i1 * N_TOK + n];
        fscore[n] = fscore[n] + 0.7f * (p0 * sa + p1 * sb);
    }
}

// ---------------------------------------------------------------------------
// Aux loss from per-block prob partial sums (192 blocks x 5 experts).
// ---------------------------------------------------------------------------
__global__ __launch_bounds__(256)
void aux_kernel(const float* __restrict__ part, float* __restrict__ aux)
{
    __shared__ float avg[5];
    const int tid = threadIdx.x;
    if (tid < 5) {
        float s = 0.f;
        for (int b = 0; b < 192; ++b) s += part[b * 5 + tid];
        avg[tid] = s / (float)N_TOK;
    }
    __syncthreads();
    if (tid == 0) {
        float ent = 0.f, l2 = 0.f;
        #pragma unroll
        for (int e = 0; e < 5; ++e) {
            ent -= avg[e] * logf(avg[e] + 1e-8f);
            float d = avg[e] - 0.2f;
            l2 += d * d;
        }
        l2 *= (1.0f / 5.0f);
        aux[0] = -ent * 0.01f + 0.01f * l2;
    }
}

// ---------------------------------------------------------------------------
extern "C" void kernel_launch(void* const* d_in, const int* in_sizes, int n_in,
                              void* d_out, int out_size, void* d_ws, size_t ws_size,
                              hipStream_t stream)
{
    (void)in_sizes; (void)n_in; (void)out_size; (void)ws_size;

    const float* x     = (const float*)d_in[0];
    const float* rw1   = (const float*)d_in[1];
    const float* rb1   = (const float*)d_in[2];
    const float* rw2   = (const float*)d_in[3];
    const float* rb2   = (const float*)d_in[4];
    const float* rw3   = (const float*)d_in[5];
    const float* rb3   = (const float*)d_in[6];
    const float* shtw1 = (const float*)d_in[7];
    const float* shtb1 = (const float*)d_in[8];
    const float* shtw2 = (const float*)d_in[9];
    const float* shtb2 = (const float*)d_in[10];
    const float* shtw3 = (const float*)d_in[11];
    const float* shtb3 = (const float*)d_in[12];
    const float* shsw1 = (const float*)d_in[13];
    const float* shsb1 = (const float*)d_in[14];
    const float* shsw2 = (const float*)d_in[15];
    const float* shsb2 = (const float*)d_in[16];
    const float* shsw3 = (const float*)d_in[17];
    const float* shsb3 = (const float*)d_in[18];
    const float* extw1 = (const float*)d_in[19];
    const float* extb1 = (const float*)d_in[20];
    const float* extw2 = (const float*)d_in[21];
    const float* extb2 = (const float*)d_in[22];
    const float* extw3 = (const float*)d_in[23];
    const float* extb3 = (const float*)d_in[24];
    const float* exsw1 = (const float*)d_in[25];
    const float* exsb1 = (const float*)d_in[26];
    const float* exsw2 = (const float*)d_in[27];
    const float* exsb2 = (const float*)d_in[28];
    const float* exsw3 = (const float*)d_in[29];
    const float* exsb3 = (const float*)d_in[30];

    float* out = (float*)d_out;

    // workspace layout (72.8 MiB total)
    char* ws   = (char*)d_ws;
    void* buf1 = (void*)(ws);                     // up to N*256 fp32 = 50,331,648 B
    void* buf2 = (void*)(ws + 50331648);          // up to N*256 bf16 / N*128 fp32 = 25,165,824 B
    float* tp  = (float*)(ws + 75497472);         // N*2 fp32
    int*   ti  = (int*)  (ws + 75890688);         // N*2 int32
    float* part= (float*)(ws + 76283904);         // 192*5 fp32

    const dim3 blk(256);
    const dim3 g1(N_TOK / 128, 1);
    const dim3 g2(N_TOK / 128, 2);

    // ---- router (pure fp32: topk_idx must match the reference ordering) ----
    mlp_gemm<false, false, true ><<<g2, blk, 0, stream>>>(x,    rw1, rb1, buf1, 128, 256, 1.0f);
    mlp_gemm<false, false, true ><<<g1, blk, 0, stream>>>(buf1, rw2, rb2, buf2, 256, 128, 1.0f);
    mlp_gemm<false, false, false><<<g1, blk, 0, stream>>>(buf2, rw3, rb3, out + OFF_LOGITS, 128, 5, 1.0f);

    // ---- shared trajectory expert: writes 0.3*out directly to final_traj ----
    mlp_gemm<false, true,  true ><<<g2, blk, 0, stream>>>(x,    shtw1, shtb1, buf1, 128, 256, 1.0f);
    mlp_gemm<true,  true,  true ><<<g2, blk, 0, stream>>>(buf1, shtw2, shtb2, buf2, 256, 256, 1.0f);
    mlp_gemm<true,  false, false><<<g1, blk, 0, stream>>>(buf2, shtw3, shtb3, out + OFF_TRAJ, 256, 120, 0.3f);

    // ---- shared score expert: writes 0.3*out to final_score ----
    mlp_gemm<false, true,  true ><<<g1, blk, 0, stream>>>(x,    shsw1, shsb1, buf1, 128, 128, 1.0f);
    mlp_gemm<true,  true,  true ><<<g1, blk, 0, stream>>>(buf1, shsw2, shsb2, buf2, 128, 64, 1.0f);
    mlp_gemm<true,  false, false><<<g1, blk, 0, stream>>>(buf2, shsw3, shsb3, out + OFF_SCORE, 64, 1, 0.3f);

    // ---- unshared experts (dense over all tokens, like the reference) ----
    for (int e = 0; e < NE; ++e) {
        mlp_gemm<false, true,  true ><<<g2, blk, 0, stream>>>(
            x,    extw1 + (size_t)e * 128 * 256, extb1 + (size_t)e * 256, buf1, 128, 256, 1.0f);
        mlp_gemm<true,  true,  true ><<<g2, blk, 0, stream>>>(
            buf1, extw2 + (size_t)e * 256 * 256, extb2 + (size_t)e * 256, buf2, 256, 256, 1.0f);
        mlp_gemm<true,  false, false><<<g1, blk, 0, stream>>>(
            buf2, extw3 + (size_t)e * 256 * 120, extb3 + (size_t)e * 120,
            out + OFF_TRAJALL + (size_t)e * N_TOK * 120, 256, 120, 1.0f);

        mlp_gemm<false, true,  true ><<<g1, blk, 0, stream>>>(
            x,    exsw1 + (size_t)e * 128 * 128, exsb1 + (size_t)e * 128, buf1, 128, 128, 1.0f);
        mlp_gemm<true,  true,  true ><<<g1, blk, 0, stream>>>(
            buf1, exsw2 + (size_t)e * 128 * 64,  exsb2 + (size_t)e * 64,  buf2, 128, 64, 1.0f);
        mlp_gemm<true,  false, false><<<g1, blk, 0, stream>>>(
            buf2, exsw3 + (size_t)e * 64,        exsb3 + (size_t)e,
            out + OFF_SCOREALL + (size_t)e * N_TOK, 64, 1, 1.0f);
    }

    // ---- router post: probs partials, top-2, top-2 softmax ----
    router_post<<<dim3(192), blk, 0, stream>>>(out + OFF_LOGITS, out + OFF_IDX, tp, ti, part);

    // ---- combine: add 0.7 * gathered expert outputs onto 0.3*shared ----
    combine_kernel<<<dim3((N_TOK * 120) / 256), blk, 0, stream>>>(
        out + OFF_TRAJALL, out + OFF_SCOREALL, tp, ti, out + OFF_TRAJ, out + OFF_SCORE);

    // ---- aux loss ----
    aux_kernel<<<dim3(1), blk, 0, stream>>>(part, out + OFF_AUX);
}

// Round 2
// 770.060 us; speedup vs baseline: 2.8748x; 2.8748x over previous
//
#include <hip/hip_runtime.h>
#include <hip/hip_bf16.h>
#include <cstdint>
#include <cstddef>

// Problem constants
static constexpr int N_TOK = 49152;     // B*M = 8192*6
static constexpr int NE    = 5;         // experts
// d_out offsets (floats), outputs concatenated in reference return order
static constexpr size_t OFF_TRAJ     = 0;          // [N,120]
static constexpr size_t OFF_SCORE    = 5898240;    // [N]
static constexpr size_t OFF_LOGITS   = 5947392;    // [N,5]
static constexpr size_t OFF_IDX      = 6193152;    // [N,2]  (ints stored as floats)
static constexpr size_t OFF_AUX      = 6291456;    // [1]
static constexpr size_t OFF_TRAJALL  = 6291457;    // [5,N,120]
static constexpr size_t OFF_SCOREALL = 35782657;   // [5,N]

typedef short s16x8 __attribute__((ext_vector_type(8)));
typedef float f32x4 __attribute__((ext_vector_type(4)));
typedef unsigned int u32;
typedef unsigned short u16;

__device__ __forceinline__ float gelu_f(float x) {
    return 0.5f * x * (1.0f + erff(x * 0.70710678118654752440f));
}
__device__ __forceinline__ float bf2f(u16 u) {
    return __uint_as_float(((u32)u) << 16);
}

// async global->LDS, 16B per lane. LDS dest must be wave-uniform base + lane*16.
__device__ __forceinline__ void gload16(const u16* g, u16* l) {
    __builtin_amdgcn_global_load_lds(
        (const __attribute__((address_space(1))) u32*)g,
        (__attribute__((address_space(3))) u32*)l, 16, 0, 0);
}

// ---------------------------------------------------------------------------
// fp32 tile GEMM (router only; topk_idx needs fp32-exact logits).
// ---------------------------------------------------------------------------
template<bool GELU>
__global__ __launch_bounds__(256)
void mlp_gemm(const float* __restrict__ A, const float* __restrict__ W,
              const float* __restrict__ bias, float* __restrict__ C,
              int Kd, int H)
{
    __shared__ float As[16][128];
    __shared__ float Ws[16][128];

    const int tid  = threadIdx.x;
    const int tx   = tid & 15;
    const int ty   = tid >> 4;
    const int row0 = blockIdx.x * 128;
    const int col0 = blockIdx.y * 128;
    const int lm = tid >> 1;
    const int lk = (tid & 1) * 8;

    float acc[8][8] = {};

    for (int k0 = 0; k0 < Kd; k0 += 16) {
        const float* src = A + (size_t)(row0 + lm) * Kd + k0 + lk;
        float4 f0 = *(const float4*)src;
        float4 f1 = *(const float4*)(src + 4);
        As[lk + 0][lm] = f0.x; As[lk + 1][lm] = f0.y;
        As[lk + 2][lm] = f0.z; As[lk + 3][lm] = f0.w;
        As[lk + 4][lm] = f1.x; As[lk + 5][lm] = f1.y;
        As[lk + 6][lm] = f1.z; As[lk + 7][lm] = f1.w;
        {
            const int wc = col0 + tx * 8;
            if (wc + 8 <= H) {
                const float* wsrc = W + (size_t)(k0 + ty) * H + wc;
                float4 g0 = *(const float4*)wsrc;
                float4 g1 = *(const float4*)(wsrc + 4);
                *(float4*)&Ws[ty][tx * 8]     = g0;
                *(float4*)&Ws[ty][tx * 8 + 4] = g1;
            } else {
                #pragma unroll
                for (int j = 0; j < 8; ++j) {
                    int c = wc + j;
                    Ws[ty][tx * 8 + j] = (c < H) ? W[(size_t)(k0 + ty) * H + c] : 0.0f;
                }
            }
        }
        __syncthreads();
        #pragma unroll
        for (int kk = 0; kk < 16; ++kk) {
            float a[8], w[8];
            *(float4*)&a[0] = *(const float4*)&As[kk][ty * 8];
            *(float4*)&a[4] = *(const float4*)&As[kk][ty * 8 + 4];
            *(float4*)&w[0] = *(const float4*)&Ws[kk][tx * 8];
            *(float4*)&w[4] = *(const float4*)&Ws[kk][tx * 8 + 4];
            #pragma unroll
            for (int i = 0; i < 8; ++i)
                #pragma unroll
                for (int j = 0; j < 8; ++j)
                    acc[i][j] = fmaf(a[i], w[j], acc[i][j]);
        }
        __syncthreads();
    }

    #pragma unroll
    for (int i = 0; i < 8; ++i) {
        const int r = row0 + ty * 8 + i;
        #pragma unroll
        for (int j = 0; j < 8; ++j) {
            const int c = col0 + tx * 8 + j;
            if (c < H) {
                float v = acc[i][j] + bias[c];
                if (GELU) v = gelu_f(v);
                C[(size_t)r * H + c] = v;
            }
        }
    }
}

// ---------------------------------------------------------------------------
// MFMA bf16 GEMM: C[N,H] = act(A[N,K] @ Bt[H,K]^T + bias) * alpha
// 128x128 tile, BK=64, 4 waves (64x64 each, 4x4 frags of 16x16x32).
// A, Bt bf16; bias fp32; out fp32 or bf16. H<=128*gridDim.y (store-guarded).
// Expert batching via blockIdx.z with element strides.
// ---------------------------------------------------------------------------
template<bool OUTBF16, bool GELU>
__global__ __launch_bounds__(256)
void gemm_bf16(const u16* __restrict__ A, const u16* __restrict__ Bt,
               const float* __restrict__ bias, void* __restrict__ Cp,
               int K, int H, float alpha,
               size_t aStrideZ, size_t bStrideZ, size_t biasStrideZ, size_t cStrideZ)
{
    __shared__ u16 As[128 * 64];
    __shared__ u16 Bs[128 * 64];

    const int z = blockIdx.z;
    A    += (size_t)z * aStrideZ;
    Bt   += (size_t)z * bStrideZ;
    bias += (size_t)z * biasStrideZ;

    const int tid  = threadIdx.x;
    const int lane = tid & 63;
    const int wave = tid >> 6;
    const int row0 = blockIdx.x * 128;
    const int col0 = blockIdx.y * 128;

    // staging: wave w covers rows w*32..w*32+31 of each tile, 8 rows/instr
    const int sr = (lane >> 3);        // 0..7 row within instr group
    const int sc = (lane & 7);         // dest 16B slot within 128B row

    f32x4 acc[4][4] = {};

    for (int k0 = 0; k0 < K; k0 += 64) {
        __syncthreads();   // previous compute done before overwrite
        #pragma unroll
        for (int i = 0; i < 4; ++i) {
            const int r  = wave * 32 + i * 8 + sr;       // tile row (also LDS row)
            const int cc = sc ^ (r & 7);                 // inverse-swizzled source chunk
            const u16* ga = A + (size_t)(row0 + r) * K + k0 + cc * 8;
            gload16(ga, &As[(wave * 32 + i * 8) * 64 + lane * 8]);
            int rb = col0 + r; if (rb > H - 1) rb = H - 1;   // clamp (stores guarded)
            const u16* gb = Bt + (size_t)rb * K + k0 + cc * 8;
            gload16(gb, &Bs[(wave * 32 + i * 8) * 64 + lane * 8]);
        }
        __syncthreads();   // drains vmcnt(0): LDS tiles ready

        #pragma unroll
        for (int s = 0; s < 2; ++s) {
            s16x8 a[4], b[4];
            #pragma unroll
            for (int m = 0; m < 4; ++m) {
                const int r = (wave >> 1) * 64 + m * 16 + (lane & 15);
                const int c = (s * 4 + (lane >> 4)) ^ (r & 7);
                a[m] = *(const s16x8*)&As[r * 64 + c * 8];
            }
            #pragma unroll
            for (int n = 0; n < 4; ++n) {
                const int r = (wave & 1) * 64 + n * 16 + (lane & 15);
                const int c = (s * 4 + (lane >> 4)) ^ (r & 7);
                b[n] = *(const s16x8*)&Bs[r * 64 + c * 8];
            }
            #pragma unroll
            for (int m = 0; m < 4; ++m)
                #pragma unroll
                for (int n = 0; n < 4; ++n)
                    acc[m][n] = __builtin_amdgcn_mfma_f32_16x16x32_bf16(a[m], b[n], acc[m][n], 0, 0, 0);
        }
    }

    // epilogue: C/D layout col=lane&15, row=(lane>>4)*4+j
    #pragma unroll
    for (int m = 0; m < 4; ++m) {
        const int rbase = row0 + (wave >> 1) * 64 + m * 16 + (lane >> 4) * 4;
        #pragma unroll
        for (int n = 0; n < 4; ++n) {
            const int c = col0 + (wave & 1) * 64 + n * 16 + (lane & 15);
            if (c < H) {
                const float bb = bias[c];
                #pragma unroll
                for (int j = 0; j < 4; ++j) {
                    float v = acc[m][n][j] + bb;
                    if (GELU) v = gelu_f(v);
                    v *= alpha;
                    const size_t off = (size_t)z * cStrideZ + (size_t)(rbase + j) * H + c;
                    if (OUTBF16) ((u16*)Cp)[off] = ((__hip_bfloat16_raw)__float2bfloat16(v)).x;
                    else         ((float*)Cp)[off] = v;
                }
            }
        }
    }
}

// ---------------------------------------------------------------------------
// x fp32 -> bf16 (4 elems/thread)
// ---------------------------------------------------------------------------
__global__ __launch_bounds__(256)
void convert_x(const float* __restrict__ x, u16* __restrict__ xb)
{
    const size_t i = ((size_t)blockIdx.x * 256 + threadIdx.x) * 4;
    float4 v = *(const float4*)(x + i);
    ushort4 o;
    o.x = ((__hip_bfloat16_raw)__float2bfloat16(v.x)).x;
    o.y = ((__hip_bfloat16_raw)__float2bfloat16(v.y)).x;
    o.z = ((__hip_bfloat16_raw)__float2bfloat16(v.z)).x;
    o.w = ((__hip_bfloat16_raw)__float2bfloat16(v.w)).x;
    *(ushort4*)(xb + i) = o;
}

// ---------------------------------------------------------------------------
// Weight convert+transpose: src fp32 [nz][K][H] -> dst bf16 [nz][H][K]
// ---------------------------------------------------------------------------
struct WDesc { const float* src; unsigned int dstOff; int K, H, nz; };
struct WTable { WDesc d[10]; };

__global__ __launch_bounds__(256)
void convert_w(WTable t, u16* __restrict__ dst)
{
    const WDesc dd = t.d[blockIdx.y];
    const int total = dd.K * dd.H * dd.nz;
    const int idx = blockIdx.x * 256 + threadIdx.x;
    if (idx < total) {
        const int kh = dd.K * dd.H;
        const int e = idx / kh;
        const int r = idx - e * kh;
        const int h = r / dd.K;
        const int k = r - h * dd.K;
        const float v = dd.src[(size_t)e * kh + (size_t)k * dd.H + h];
        dst[dd.dstOff + idx] = ((__hip_bfloat16_raw)__float2bfloat16(v)).x;
    }
}

// ---------------------------------------------------------------------------
// Score L3: out[n] = alpha * (dot(h2[n,0:64], w) + b)
// ---------------------------------------------------------------------------
__global__ __launch_bounds__(256)
void score_l3(const u16* __restrict__ h2, const float* __restrict__ w,
              const float* __restrict__ b, float* __restrict__ outp, float alpha)
{
    const int n = blockIdx.x * 256 + threadIdx.x;
    const u16* p = h2 + (size_t)n * 64;
    float s = 0.f;
    #pragma unroll
    for (int i = 0; i < 8; ++i) {
        s16x8 v = *(const s16x8*)(p + i * 8);
        #pragma unroll
        for (int j = 0; j < 8; ++j)
            s = fmaf(bf2f((u16)v[j]), w[i * 8 + j], s);
    }
    outp[n] = alpha * (s + b[0]);
}

// ---------------------------------------------------------------------------
// Router post-process: softmax partials (aux), top-2, top-2 softmax.
// ---------------------------------------------------------------------------
__global__ __launch_bounds__(256)
void router_post(const float* __restrict__ logits, float* __restrict__ oidx,
                 float* __restrict__ tp, int* __restrict__ ti,
                 float* __restrict__ part)
{
    const int tid = threadIdx.x;
    const int n = blockIdx.x * 256 + tid;

    float l[5];
    #pragma unroll
    for (int e = 0; e < 5; ++e) l[e] = logits[(size_t)n * 5 + e];

    float m = l[0];
    #pragma unroll
    for (int e = 1; e < 5; ++e) m = fmaxf(m, l[e]);
    float p[5], s = 0.f;
    #pragma unroll
    for (int e = 0; e < 5; ++e) { p[e] = expf(l[e] - m); s += p[e]; }
    const float inv = 1.0f / s;

    __shared__ float red[256];
    #pragma unroll
    for (int e = 0; e < 5; ++e) {
        red[tid] = p[e] * inv;
        __syncthreads();
        for (int off = 128; off > 0; off >>= 1) {
            if (tid < off) red[tid] += red[tid + off];
            __syncthreads();
        }
        if (tid == 0) part[blockIdx.x * 5 + e] = red[0];
        __syncthreads();
    }

    int i0 = 0; float v0 = l[0];
    #pragma unroll
    for (int e = 1; e < 5; ++e) if (l[e] > v0) { v0 = l[e]; i0 = e; }
    int i1 = -1; float v1 = -1e30f;
    #pragma unroll
    for (int e = 0; e < 5; ++e) if (e != i0 && l[e] > v1) { v1 = l[e]; i1 = e; }

    const float t  = expf(v1 - v0);
    const float q0 = 1.0f / (1.0f + t);
    const float q1 = t / (1.0f + t);

    oidx[(size_t)n * 2]     = (float)i0;
    oidx[(size_t)n * 2 + 1] = (float)i1;
    tp[n * 2] = q0; tp[n * 2 + 1] = q1;
    ti[n * 2] = i0; ti[n * 2 + 1] = i1;
}

// ---------------------------------------------------------------------------
// Combine: final += 0.7 * sum_k p_k * expert_out[i_k]
// ---------------------------------------------------------------------------
__global__ __launch_bounds__(256)
void combine_kernel(const float* __restrict__ trajall, const float* __restrict__ scoreall,
                    const float* __restrict__ tp, const int* __restrict__ ti,
                    float* __restrict__ ftraj, float* __restrict__ fscore)
{
    const size_t i = (size_t)blockIdx.x * 256 + threadIdx.x;   // < N*120
    const int n = (int)(i / 120);
    const int q = (int)(i - (size_t)n * 120);
    const int i0 = ti[n * 2], i1 = ti[n * 2 + 1];
    const float p0 = tp[n * 2], p1 = tp[n * 2 + 1];

    const float a = trajall[((size_t)i0 * N_TOK + n) * 120 + q];
    const float b = trajall[((size_t)i1 * N_TOK + n) * 120 + q];
    ftraj[i] = ftraj[i] + 0.7f * (p0 * a + p1 * b);

    if (q == 0) {
        const float sa = scoreall[(size_t)i0 * N_TOK + n];
        const float sb = scoreall[(size_t)i1 * N_TOK + n];
        fscore[n] = fscore[n] + 0.7f * (p0 * sa + p1 * sb);
    }
}

__global__ __launch_bounds__(256)
void aux_kernel(const float* __restrict__ part, float* __restrict__ aux)
{
    __shared__ float avg[5];
    const int tid = threadIdx.x;
    if (tid < 5) {
        float s = 0.f;
        for (int b = 0; b < 192; ++b) s += part[b * 5 + tid];
        avg[tid] = s / (float)N_TOK;
    }
    __syncthreads();
    if (tid == 0) {
        float ent = 0.f, l2 = 0.f;
        #pragma unroll
        for (int e = 0; e < 5; ++e) {
            ent -= avg[e] * logf(avg[e] + 1e-8f);
            float d = avg[e] - 0.2f;
            l2 += d * d;
        }
        l2 *= (1.0f / 5.0f);
        aux[0] = -ent * 0.01f + 0.01f * l2;
    }
}

// ---------------------------------------------------------------------------
extern "C" void kernel_launch(void* const* d_in, const int* in_sizes, int n_in,
                              void* d_out, int out_size, void* d_ws, size_t ws_size,
                              hipStream_t stream)
{
    (void)in_sizes; (void)n_in; (void)out_size; (void)ws_size;

    const float* x     = (const float*)d_in[0];
    const float* rw1   = (const float*)d_in[1];
    const float* rb1   = (const float*)d_in[2];
    const float* rw2   = (const float*)d_in[3];
    const float* rb2   = (const float*)d_in[4];
    const float* rw3   = (const float*)d_in[5];
    const float* rb3   = (const float*)d_in[6];
    const float* shtb1 = (const float*)d_in[8];
    const float* shtb2 = (const float*)d_in[10];
    const float* shtb3 = (const float*)d_in[12];
    const float* shsb1 = (const float*)d_in[14];
    const float* shsb2 = (const float*)d_in[16];
    const float* shsw3 = (const float*)d_in[17];
    const float* shsb3 = (const float*)d_in[18];
    const float* extb1 = (const float*)d_in[20];
    const float* extb2 = (const float*)d_in[22];
    const float* extb3 = (const float*)d_in[24];
    const float* exsb1 = (const float*)d_in[26];
    const float* exsb2 = (const float*)d_in[28];
    const float* exsw3 = (const float*)d_in[29];
    const float* exsb3 = (const float*)d_in[30];

    float* out = (float*)d_out;

    // ---- workspace layout (peak 76.3 MB, same as round 1) ----
    char* ws = (char*)d_ws;
    // phase 1 (router): rh1 fp32 [N,256] @0, rh2 fp32 [N,128] @50331648
    float* rh1 = (float*)(ws);
    float* rh2 = (float*)(ws + 50331648);
    // phase 2 (experts, reuses router space):
    u16* xb   = (u16*)(ws);                  // [N,128] bf16, 12,582,912 B
    u16* buf1 = (u16*)(ws + 12582912);       // [N,256] bf16, 25,165,824 B
    u16* buf2 = (u16*)(ws + 37748736);       // [N,256] bf16, 25,165,824 B
    u16* wtb  = (u16*)(ws + 62914560);       // transposed bf16 weights, 1,843,200 B
    // tails (beyond 75,497,472)
    float* tp  = (float*)(ws + 75497472);
    int*   ti  = (int*)  (ws + 75890688);
    float* part= (float*)(ws + 76283904);

    // transposed-weight offsets (u16 elems)
    const u32 O_SHTW1 = 0,      O_SHTW2 = 32768,  O_SHTW3 = 98304;
    const u32 O_SHSW1 = 129024, O_SHSW2 = 145408;
    const u32 O_EXTW1 = 153600, O_EXTW2 = 317440, O_EXTW3 = 645120;
    const u32 O_EXSW1 = 798720, O_EXSW2 = 880640;

    const dim3 blk(256);
    const dim3 g1(N_TOK / 128, 1);
    const dim3 g2(N_TOK / 128, 2);

    // ---- router (fp32 exact: topk_idx must match reference ordering) ----
    mlp_gemm<true ><<<g2, blk, 0, stream>>>(x,   rw1, rb1, rh1, 128, 256);
    mlp_gemm<true ><<<g1, blk, 0, stream>>>(rh1, rw2, rb2, rh2, 256, 128);
    mlp_gemm<false><<<g1, blk, 0, stream>>>(rh2, rw3, rb3, out + OFF_LOGITS, 128, 5);

    // ---- conversions (after router: reuse rh1/rh2 space) ----
    convert_x<<<dim3(N_TOK * 128 / 1024), blk, 0, stream>>>(x, xb);
    {
        WTable t;
        t.d[0] = { (const float*)d_in[7],  O_SHTW1, 128, 256, 1 };
        t.d[1] = { (const float*)d_in[9],  O_SHTW2, 256, 256, 1 };
        t.d[2] = { (const float*)d_in[11], O_SHTW3, 256, 120, 1 };
        t.d[3] = { (const float*)d_in[13], O_SHSW1, 128, 128, 1 };
        t.d[4] = { (const float*)d_in[15], O_SHSW2, 128,  64, 1 };
        t.d[5] = { (const float*)d_in[19], O_EXTW1, 128, 256, 5 };
        t.d[6] = { (const float*)d_in[21], O_EXTW2, 256, 256, 5 };
        t.d[7] = { (const float*)d_in[23], O_EXTW3, 256, 120, 5 };
        t.d[8] = { (const float*)d_in[25], O_EXSW1, 128, 128, 5 };
        t.d[9] = { (const float*)d_in[27], O_EXSW2, 128,  64, 5 };
        convert_w<<<dim3(1280, 10), blk, 0, stream>>>(t, wtb);
    }

    // ---- shared trajectory expert (L3 writes 0.3*out into final_traj) ----
    gemm_bf16<true,  true ><<<g2, blk, 0, stream>>>(xb,   wtb + O_SHTW1, shtb1, buf1, 128, 256, 1.0f, 0,0,0,0);
    gemm_bf16<true,  true ><<<g2, blk, 0, stream>>>(buf1, wtb + O_SHTW2, shtb2, buf2, 256, 256, 1.0f, 0,0,0,0);
    gemm_bf16<false, false><<<g1, blk, 0, stream>>>(buf2, wtb + O_SHTW3, shtb3, out + OFF_TRAJ, 256, 120, 0.3f, 0,0,0,0);

    // ---- shared score expert ----
    gemm_bf16<true,  true ><<<g1, blk, 0, stream>>>(xb,   wtb + O_SHSW1, shsb1, buf1, 128, 128, 1.0f, 0,0,0,0);
    gemm_bf16<true,  true ><<<g1, blk, 0, stream>>>(buf1, wtb + O_SHSW2, shsb2, buf2, 128, 64, 1.0f, 0,0,0,0);
    score_l3<<<dim3(192), blk, 0, stream>>>(buf2, shsw3, shsb3, out + OFF_SCORE, 0.3f);

    // ---- unshared experts ----
    for (int e = 0; e < NE; ++e) {
        gemm_bf16<true,  true ><<<g2, blk, 0, stream>>>(
            xb,   wtb + O_EXTW1 + (size_t)e * 32768, extb1 + (size_t)e * 256, buf1, 128, 256, 1.0f, 0,0,0,0);
        gemm_bf16<true,  true ><<<g2, blk, 0, stream>>>(
            buf1, wtb + O_EXTW2 + (size_t)e * 65536, extb2 + (size_t)e * 256, buf2, 256, 256, 1.0f, 0,0,0,0);
        gemm_bf16<false, false><<<g1, blk, 0, stream>>>(
            buf2, wtb + O_EXTW3 + (size_t)e * 30720, extb3 + (size_t)e * 120,
            out + OFF_TRAJALL + (size_t)e * N_TOK * 120, 256, 120, 1.0f, 0,0,0,0);

        gemm_bf16<true,  true ><<<g1, blk, 0, stream>>>(
            xb,   wtb + O_EXSW1 + (size_t)e * 16384, exsb1 + (size_t)e * 128, buf1, 128, 128, 1.0f, 0,0,0,0);
        gemm_bf16<true,  true ><<<g1, blk, 0, stream>>>(
            buf1, wtb + O_EXSW2 + (size_t)e * 8192,  exsb2 + (size_t)e * 64,  buf2, 128, 64, 1.0f, 0,0,0,0);
        score_l3<<<dim3(192), blk, 0, stream>>>(
            buf2, exsw3 + (size_t)e * 64, exsb3 + (size_t)e, out + OFF_SCOREALL + (size_t)e * N_TOK, 1.0f);
    }

    // ---- router post, combine, aux ----
    router_post<<<dim3(192), blk, 0, stream>>>(out + OFF_LOGITS, out + OFF_IDX, tp, ti, part);
    combine_kernel<<<dim3((N_TOK * 120) / 256), blk, 0, stream>>>(
        out + OFF_TRAJALL, out + OFF_SCOREALL, tp, ti, out + OFF_TRAJ, out + OFF_SCORE);
    aux_kernel<<<dim3(1), blk, 0, stream>>>(part, out + OFF_AUX);
}

// Round 3
// 592.999 us; speedup vs baseline: 3.7331x; 1.2986x over previous
//
#include <hip/hip_runtime.h>
#include <hip/hip_bf16.h>
#include <cstdint>
#include <cstddef>

// Problem constants
static constexpr int N_TOK = 49152;     // B*M = 8192*6
// d_out offsets (floats), outputs concatenated in reference return order
static constexpr size_t OFF_TRAJ     = 0;          // [N,120]
static constexpr size_t OFF_SCORE    = 5898240;    // [N]
static constexpr size_t OFF_LOGITS   = 5947392;    // [N,5]
static constexpr size_t OFF_IDX      = 6193152;    // [N,2]  (ints stored as floats)
static constexpr size_t OFF_AUX      = 6291456;    // [1]
static constexpr size_t OFF_TRAJALL  = 6291457;    // [5,N,120]
static constexpr size_t OFF_SCOREALL = 35782657;   // [5,N]

typedef short s16x8 __attribute__((ext_vector_type(8)));
typedef float f32x4 __attribute__((ext_vector_type(4)));
typedef unsigned int u32;
typedef unsigned short u16;

__device__ __forceinline__ float gelu_f(float x) {
    return 0.5f * x * (1.0f + erff(x * 0.70710678118654752440f));
}
__device__ __forceinline__ float bf2f(u16 u) {
    return __uint_as_float(((u32)u) << 16);
}
__device__ __forceinline__ void gload16(const u16* g, u16* l) {
    __builtin_amdgcn_global_load_lds(
        (const __attribute__((address_space(1))) u32*)g,
        (__attribute__((address_space(3))) u32*)l, 16, 0, 0);
}

// ---------------------------------------------------------------------------
// fp32 tile GEMM (router L1/L2 only; topk_idx needs fp32-exact logits).
// Ws padded to 132 floats/row: float4 stores go 16-way -> 4-way bank conflict.
// ---------------------------------------------------------------------------
template<bool GELU>
__global__ __launch_bounds__(256)
void mlp_gemm(const float* __restrict__ A, const float* __restrict__ W,
              const float* __restrict__ bias, float* __restrict__ C,
              int Kd, int H)
{
    __shared__ float As[16][128];
    __shared__ float Ws[16][132];

    const int tid  = threadIdx.x;
    const int tx   = tid & 15;
    const int ty   = tid >> 4;
    const int row0 = blockIdx.x * 128;
    const int col0 = blockIdx.y * 128;
    const int lm = tid >> 1;
    const int lk = (tid & 1) * 8;

    float acc[8][8] = {};

    for (int k0 = 0; k0 < Kd; k0 += 16) {
        const float* src = A + (size_t)(row0 + lm) * Kd + k0 + lk;
        float4 f0 = *(const float4*)src;
        float4 f1 = *(const float4*)(src + 4);
        As[lk + 0][lm] = f0.x; As[lk + 1][lm] = f0.y;
        As[lk + 2][lm] = f0.z; As[lk + 3][lm] = f0.w;
        As[lk + 4][lm] = f1.x; As[lk + 5][lm] = f1.y;
        As[lk + 6][lm] = f1.z; As[lk + 7][lm] = f1.w;
        {
            const float* wsrc = W + (size_t)(k0 + ty) * H + col0 + tx * 8;
            float4 g0 = *(const float4*)wsrc;
            float4 g1 = *(const float4*)(wsrc + 4);
            *(float4*)&Ws[ty][tx * 8]     = g0;
            *(float4*)&Ws[ty][tx * 8 + 4] = g1;
        }
        __syncthreads();
        #pragma unroll
        for (int kk = 0; kk < 16; ++kk) {
            float a[8], w[8];
            *(float4*)&a[0] = *(const float4*)&As[kk][ty * 8];
            *(float4*)&a[4] = *(const float4*)&As[kk][ty * 8 + 4];
            *(float4*)&w[0] = *(const float4*)&Ws[kk][tx * 8];
            *(float4*)&w[4] = *(const float4*)&Ws[kk][tx * 8 + 4];
            #pragma unroll
            for (int i = 0; i < 8; ++i)
                #pragma unroll
                for (int j = 0; j < 8; ++j)
                    acc[i][j] = fmaf(a[i], w[j], acc[i][j]);
        }
        __syncthreads();
    }

    #pragma unroll
    for (int i = 0; i < 8; ++i) {
        const int r = row0 + ty * 8 + i;
        #pragma unroll
        for (int j = 0; j < 8; ++j) {
            const int c = col0 + tx * 8 + j;
            float v = acc[i][j] + bias[c];
            if (GELU) v = gelu_f(v);
            C[(size_t)r * H + c] = v;
        }
    }
}

// ---------------------------------------------------------------------------
// Router L3 + softmax partials + top-2 (fused). rh2:[N,128] fp32, w3:[128,5].
// ---------------------------------------------------------------------------
__global__ __launch_bounds__(256)
void router_l3post(const float* __restrict__ rh2, const float* __restrict__ w3,
                   const float* __restrict__ b3, float* __restrict__ logits,
                   float* __restrict__ oidx, float* __restrict__ tp,
                   int* __restrict__ ti, float* __restrict__ part)
{
    __shared__ float w3s[640];
    __shared__ float red[256];
    const int tid = threadIdx.x;
    for (int i = tid; i < 640; i += 256) w3s[i] = w3[i];
    __syncthreads();

    const int n = blockIdx.x * 256 + tid;
    const float* h = rh2 + (size_t)n * 128;

    float l[5];
    #pragma unroll
    for (int e = 0; e < 5; ++e) l[e] = b3[e];
    for (int k = 0; k < 128; k += 4) {
        float4 hv = *(const float4*)(h + k);
        #pragma unroll
        for (int e = 0; e < 5; ++e) {
            l[e] = fmaf(hv.x, w3s[(k + 0) * 5 + e], l[e]);
            l[e] = fmaf(hv.y, w3s[(k + 1) * 5 + e], l[e]);
            l[e] = fmaf(hv.z, w3s[(k + 2) * 5 + e], l[e]);
            l[e] = fmaf(hv.w, w3s[(k + 3) * 5 + e], l[e]);
        }
    }
    #pragma unroll
    for (int e = 0; e < 5; ++e) logits[(size_t)n * 5 + e] = l[e];

    // full softmax (aux loss partials)
    float m = l[0];
    #pragma unroll
    for (int e = 1; e < 5; ++e) m = fmaxf(m, l[e]);
    float p[5], s = 0.f;
    #pragma unroll
    for (int e = 0; e < 5; ++e) { p[e] = expf(l[e] - m); s += p[e]; }
    const float inv = 1.0f / s;

    #pragma unroll
    for (int e = 0; e < 5; ++e) {
        red[tid] = p[e] * inv;
        __syncthreads();
        for (int off = 128; off > 0; off >>= 1) {
            if (tid < off) red[tid] += red[tid + off];
            __syncthreads();
        }
        if (tid == 0) part[blockIdx.x * 5 + e] = red[0];
        __syncthreads();
    }

    // top-2 (ties keep lower index, matching jax.lax.top_k)
    int i0 = 0; float v0 = l[0];
    #pragma unroll
    for (int e = 1; e < 5; ++e) if (l[e] > v0) { v0 = l[e]; i0 = e; }
    int i1 = -1; float v1 = -1e30f;
    #pragma unroll
    for (int e = 0; e < 5; ++e) if (e != i0 && l[e] > v1) { v1 = l[e]; i1 = e; }

    const float t  = expf(v1 - v0);
    const float q0 = 1.0f / (1.0f + t);
    const float q1 = t / (1.0f + t);

    oidx[(size_t)n * 2]     = (float)i0;
    oidx[(size_t)n * 2 + 1] = (float)i1;
    tp[n * 2] = q0; tp[n * 2 + 1] = q1;
    ti[n * 2] = i0; ti[n * 2 + 1] = i1;
}

// ---------------------------------------------------------------------------
// MFMA bf16 GEMM, expert-batched over blockIdx.z (z<zSplit -> CpA+z*stride,
// else CpB). C = act(A[z] @ Bt[z]^T + bias[z]).
// 128x128 tile, BK=64, 4 waves, XOR-swizzled LDS (rule #21 both-sides).
// ---------------------------------------------------------------------------
template<bool OUTBF16, bool GELU>
__global__ __launch_bounds__(256)
void gemm_bf16(const u16* __restrict__ A, size_t aStrideZ,
               const u16* __restrict__ Bt, size_t bStrideZ,
               const float* __restrict__ bias, int biasStrideZ,
               void* __restrict__ CpA, size_t cStrideZ, void* __restrict__ CpB,
               int zSplit, int K, int H)
{
    __shared__ u16 As[128 * 64];
    __shared__ u16 Bs[128 * 64];

    const int z = blockIdx.z;
    A    += (size_t)z * aStrideZ;
    Bt   += (size_t)z * bStrideZ;
    bias += (size_t)z * biasStrideZ;

    const int tid  = threadIdx.x;
    const int lane = tid & 63;
    const int wave = tid >> 6;
    const int row0 = blockIdx.x * 128;
    const int col0 = blockIdx.y * 128;

    const int sr = (lane >> 3);
    const int sc = (lane & 7);

    f32x4 acc[4][4] = {};

    for (int k0 = 0; k0 < K; k0 += 64) {
        __syncthreads();
        #pragma unroll
        for (int i = 0; i < 4; ++i) {
            const int r  = wave * 32 + i * 8 + sr;
            const int cc = sc ^ (r & 7);
            const u16* ga = A + (size_t)(row0 + r) * K + k0 + cc * 8;
            gload16(ga, &As[(wave * 32 + i * 8) * 64 + lane * 8]);
            int rb = col0 + r; if (rb > H - 1) rb = H - 1;
            const u16* gb = Bt + (size_t)rb * K + k0 + cc * 8;
            gload16(gb, &Bs[(wave * 32 + i * 8) * 64 + lane * 8]);
        }
        __syncthreads();

        #pragma unroll
        for (int s = 0; s < 2; ++s) {
            s16x8 a[4], b[4];
            #pragma unroll
            for (int m = 0; m < 4; ++m) {
                const int r = (wave >> 1) * 64 + m * 16 + (lane & 15);
                const int c = (s * 4 + (lane >> 4)) ^ (r & 7);
                a[m] = *(const s16x8*)&As[r * 64 + c * 8];
            }
            #pragma unroll
            for (int n = 0; n < 4; ++n) {
                const int r = (wave & 1) * 64 + n * 16 + (lane & 15);
                const int c = (s * 4 + (lane >> 4)) ^ (r & 7);
                b[n] = *(const s16x8*)&Bs[r * 64 + c * 8];
            }
            #pragma unroll
            for (int m = 0; m < 4; ++m)
                #pragma unroll
                for (int n = 0; n < 4; ++n)
                    acc[m][n] = __builtin_amdgcn_mfma_f32_16x16x32_bf16(a[m], b[n], acc[m][n], 0, 0, 0);
        }
    }

    u16*   Cb = nullptr;
    float* Cf = nullptr;
    if (OUTBF16) Cb = (z < zSplit) ? (u16*)CpA + (size_t)z * cStrideZ : (u16*)CpB;
    else         Cf = (z < zSplit) ? (float*)CpA + (size_t)z * cStrideZ : (float*)CpB;

    #pragma unroll
    for (int m = 0; m < 4; ++m) {
        const int rbase = row0 + (wave >> 1) * 64 + m * 16 + (lane >> 4) * 4;
        #pragma unroll
        for (int n = 0; n < 4; ++n) {
            const int c = col0 + (wave & 1) * 64 + n * 16 + (lane & 15);
            if (c < H) {
                const float bb = bias[c];
                #pragma unroll
                for (int j = 0; j < 4; ++j) {
                    float v = acc[m][n][j] + bb;
                    if (GELU) v = gelu_f(v);
                    const size_t off = (size_t)(rbase + j) * H + c;
                    if (OUTBF16) Cb[off] = ((__hip_bfloat16_raw)__float2bfloat16(v)).x;
                    else         Cf[off] = v;
                }
            }
        }
    }
}

// ---------------------------------------------------------------------------
__global__ __launch_bounds__(256)
void convert_x(const float* __restrict__ x, u16* __restrict__ xb)
{
    const size_t i = ((size_t)blockIdx.x * 256 + threadIdx.x) * 4;
    float4 v = *(const float4*)(x + i);
    ushort4 o;
    o.x = ((__hip_bfloat16_raw)__float2bfloat16(v.x)).x;
    o.y = ((__hip_bfloat16_raw)__float2bfloat16(v.y)).x;
    o.z = ((__hip_bfloat16_raw)__float2bfloat16(v.z)).x;
    o.w = ((__hip_bfloat16_raw)__float2bfloat16(v.w)).x;
    *(ushort4*)(xb + i) = o;
}

// Weight convert+transpose: src fp32 [nz][K][H] -> dst bf16 [nz][H][K]
struct WDesc { const float* src; u32 dstOff; int K, H, nz; };
struct WTable { WDesc d[10]; };

__global__ __launch_bounds__(256)
void convert_w(WTable t, u16* __restrict__ dst)
{
    const WDesc dd = t.d[blockIdx.y];
    const int total = dd.K * dd.H * dd.nz;
    const int idx = blockIdx.x * 256 + threadIdx.x;
    if (idx < total) {
        const int kh = dd.K * dd.H;
        const int e = idx / kh;
        const int r = idx - e * kh;
        const int h = r / dd.K;
        const int k = r - h * dd.K;
        const float v = dd.src[(size_t)e * kh + (size_t)k * dd.H + h];
        dst[dd.dstOff + idx] = ((__hip_bfloat16_raw)__float2bfloat16(v)).x;
    }
}

// Flat fp32 gather-pack (biases + score L3 weights)
struct CDesc { const float* src; u32 dstOff; u32 n; };
struct CTable { CDesc d[14]; };

__global__ __launch_bounds__(256)
void pack_f32(CTable t, float* __restrict__ dst)
{
    const CDesc dd = t.d[blockIdx.y];
    const u32 i = blockIdx.x * 256 + threadIdx.x;
    if (i < dd.n) dst[dd.dstOff + i] = dd.src[i];
}

// ---------------------------------------------------------------------------
// Score L3 (batched over z): out = dot(h2[z,n,0:64], w[z]) + b[z]
// ---------------------------------------------------------------------------
__global__ __launch_bounds__(256)
void score_l3(const u16* __restrict__ h2, size_t h2StrideZ,
              const float* __restrict__ w, const float* __restrict__ b,
              float* __restrict__ outE, size_t outStrideZ, float* __restrict__ outSh)
{
    const int z = blockIdx.y;
    const int n = blockIdx.x * 256 + threadIdx.x;
    const u16* p = h2 + (size_t)z * h2StrideZ + (size_t)n * 64;
    const float* wz = w + z * 64;
    float s = 0.f;
    #pragma unroll
    for (int i = 0; i < 8; ++i) {
        s16x8 v = *(const s16x8*)(p + i * 8);
        #pragma unroll
        for (int j = 0; j < 8; ++j)
            s = fmaf(bf2f((u16)v[j]), wz[i * 8 + j], s);
    }
    const float val = s + b[z];
    if (z < 5) outE[(size_t)z * outStrideZ + n] = val;
    else       outSh[n] = val;
}

// ---------------------------------------------------------------------------
// Combine (single pass, no RMW): final = 0.3*shared + 0.7*sum_k p_k*expert[i_k]
// ---------------------------------------------------------------------------
__global__ __launch_bounds__(256)
void combine_kernel(const float* __restrict__ trajall, const float* __restrict__ scoreall,
                    const float* __restrict__ shtraj, const float* __restrict__ shscore,
                    const float* __restrict__ tp, const int* __restrict__ ti,
                    float* __restrict__ ftraj, float* __restrict__ fscore)
{
    const size_t i = (size_t)blockIdx.x * 256 + threadIdx.x;   // < N*120
    const int n = (int)(i / 120);
    const int q = (int)(i - (size_t)n * 120);
    const int i0 = ti[n * 2], i1 = ti[n * 2 + 1];
    const float p0 = tp[n * 2], p1 = tp[n * 2 + 1];

    const float a = trajall[((size_t)i0 * N_TOK + n) * 120 + q];
    const float b = trajall[((size_t)i1 * N_TOK + n) * 120 + q];
    ftraj[i] = 0.3f * shtraj[i] + 0.7f * (p0 * a + p1 * b);

    if (q == 0) {
        const float sa = scoreall[(size_t)i0 * N_TOK + n];
        const float sb = scoreall[(size_t)i1 * N_TOK + n];
        fscore[n] = 0.3f * shscore[n] + 0.7f * (p0 * sa + p1 * sb);
    }
}

__global__ __launch_bounds__(256)
void aux_kernel(const float* __restrict__ part, float* __restrict__ aux)
{
    __shared__ float avg[5];
    const int tid = threadIdx.x;
    if (tid < 5) {
        float s = 0.f;
        for (int b = 0; b < 192; ++b) s += part[b * 5 + tid];
        avg[tid] = s / (float)N_TOK;
    }
    __syncthreads();
    if (tid == 0) {
        float ent = 0.f, l2 = 0.f;
        #pragma unroll
        for (int e = 0; e < 5; ++e) {
            ent -= avg[e] * logf(avg[e] + 1e-8f);
            float d = avg[e] - 0.2f;
            l2 += d * d;
        }
        l2 *= (1.0f / 5.0f);
        aux[0] = -ent * 0.01f + 0.01f * l2;
    }
}

// ---------------------------------------------------------------------------
extern "C" void kernel_launch(void* const* d_in, const int* in_sizes, int n_in,
                              void* d_out, int out_size, void* d_ws, size_t ws_size,
                              hipStream_t stream)
{
    (void)in_sizes; (void)n_in; (void)out_size;

    const float* x   = (const float*)d_in[0];
    const float* rw1 = (const float*)d_in[1];
    const float* rb1 = (const float*)d_in[2];
    const float* rw2 = (const float*)d_in[3];
    const float* rb2 = (const float*)d_in[4];
    const float* rw3 = (const float*)d_in[5];
    const float* rb3 = (const float*)d_in[6];

    float* out = (float*)d_out;
    char* ws = (char*)d_ws;

    // ---- fixed workspace region ----
    u16*   xb      = (u16*)(ws);                         // [N,128] bf16   12,582,912 B
    u16*   wtb     = (u16*)(ws + 12582912);              // packed bf16 W   1,843,200 B
    float* biasp   = (float*)(ws + 14426368);            // packed fp32        21,336 B
    float* tp      = (float*)(ws + 14447872);            // [N,2]
    int*   ti      = (int*)  (ws + 14841088);            // [N,2]
    float* part    = (float*)(ws + 15234304);            // [192,5]
    float* shtraj  = (float*)(ws + 15238272);            // [N,120] fp32   23,592,960 B
    float* shscore = (float*)(ws + 38831232);            // [N] fp32
    const size_t FIXED_END = 39028736;

    // ---- dynamic region: router fp32 bufs, then expert bf16 bufs ----
    const size_t avail = ws_size - FIXED_END;
    int ns = N_TOK;
    while (ns > 1536 && (size_t)2 * 6 * ns * 256 * 2 > avail) ns >>= 1;

    float* rh1 = (float*)(ws + FIXED_END);               // [N,256] fp32
    float* rh2 = rh1 + (size_t)N_TOK * 256;              // [N,128] fp32
    u16* buf1 = (u16*)(ws + FIXED_END);                  // [6][ns,256] bf16
    u16* buf2 = buf1 + (size_t)6 * ns * 256;             // [6][ns,256] bf16

    // wtb offsets (u16 elems): [6][H][K] per layer, experts 0-4 then shared=5
    const u32 O_T1 = 0,      O_T2 = 196608, O_T3 = 589824;
    const u32 O_S1 = 774144, O_S2 = 872448;
    // biasp offsets (floats)
    const u32 OB_T1 = 0, OB_T2 = 1536, OB_T3 = 3072, OB_S1 = 3792, OB_S2 = 4560;
    const u32 OW_S3 = 4944, OB_S3 = 5328;

    const dim3 blk(256);

    // ---- router (fp32: topk_idx must match reference ordering exactly) ----
    mlp_gemm<true ><<<dim3(N_TOK / 128, 2), blk, 0, stream>>>(x,   rw1, rb1, rh1, 128, 256);
    mlp_gemm<true ><<<dim3(N_TOK / 128, 1), blk, 0, stream>>>(rh1, rw2, rb2, rh2, 256, 128);
    router_l3post<<<dim3(N_TOK / 256), blk, 0, stream>>>(
        rh2, rw3, rb3, out + OFF_LOGITS, out + OFF_IDX, tp, ti, part);
    aux_kernel<<<dim3(1), blk, 0, stream>>>(part, out + OFF_AUX);

    // ---- conversions / packing ----
    convert_x<<<dim3(N_TOK * 128 / 1024), blk, 0, stream>>>(x, xb);
    {
        WTable t;
        t.d[0] = { (const float*)d_in[19], O_T1,              128, 256, 5 };
        t.d[1] = { (const float*)d_in[7],  O_T1 + 5 * 32768,  128, 256, 1 };
        t.d[2] = { (const float*)d_in[21], O_T2,              256, 256, 5 };
        t.d[3] = { (const float*)d_in[9],  O_T2 + 5 * 65536,  256, 256, 1 };
        t.d[4] = { (const float*)d_in[23], O_T3,              256, 120, 5 };
        t.d[5] = { (const float*)d_in[11], O_T3 + 5 * 30720,  256, 120, 1 };
        t.d[6] = { (const float*)d_in[25], O_S1,              128, 128, 5 };
        t.d[7] = { (const float*)d_in[13], O_S1 + 5 * 16384,  128, 128, 1 };
        t.d[8] = { (const float*)d_in[27], O_S2,              128,  64, 5 };
        t.d[9] = { (const float*)d_in[15], O_S2 + 5 * 8192,   128,  64, 1 };
        convert_w<<<dim3(1280, 10), blk, 0, stream>>>(t, wtb);
    }
    {
        CTable t;
        t.d[0]  = { (const float*)d_in[20], OB_T1,        1280 };
        t.d[1]  = { (const float*)d_in[8],  OB_T1 + 1280,  256 };
        t.d[2]  = { (const float*)d_in[22], OB_T2,        1280 };
        t.d[3]  = { (const float*)d_in[10], OB_T2 + 1280,  256 };
        t.d[4]  = { (const float*)d_in[24], OB_T3,         600 };
        t.d[5]  = { (const float*)d_in[12], OB_T3 + 600,   120 };
        t.d[6]  = { (const float*)d_in[26], OB_S1,         640 };
        t.d[7]  = { (const float*)d_in[14], OB_S1 + 640,   128 };
        t.d[8]  = { (const float*)d_in[28], OB_S2,         320 };
        t.d[9]  = { (const float*)d_in[16], OB_S2 + 320,    64 };
        t.d[10] = { (const float*)d_in[29], OW_S3,         320 };
        t.d[11] = { (const float*)d_in[17], OW_S3 + 320,    64 };
        t.d[12] = { (const float*)d_in[30], OB_S3,           5 };
        t.d[13] = { (const float*)d_in[18], OB_S3 + 5,       1 };
        pack_f32<<<dim3(5, 14), blk, 0, stream>>>(t, biasp);
    }

    // ---- expert layers, batched over z=6 (experts 0-4 + shared 5) ----
    for (int s0 = 0; s0 < N_TOK; s0 += ns) {
        const u16* xbS = xb + (size_t)s0 * 128;
        float* trajAllB  = out + OFF_TRAJALL  + (size_t)s0 * 120;
        float* scoreAllB = out + OFF_SCOREALL + s0;
        const dim3 gRow(ns / 128, 1, 6), gRow2(ns / 128, 2, 6);

        // trajectory path: 128 -> 256 -> 256 -> 120
        gemm_bf16<true,  true ><<<gRow2, blk, 0, stream>>>(
            xbS, 0,            wtb + O_T1, 32768, biasp + OB_T1, 256,
            buf1, (size_t)ns * 256, nullptr, 6, 128, 256);
        gemm_bf16<true,  true ><<<gRow2, blk, 0, stream>>>(
            buf1, (size_t)ns * 256, wtb + O_T2, 65536, biasp + OB_T2, 256,
            buf2, (size_t)ns * 256, nullptr, 6, 256, 256);
        gemm_bf16<false, false><<<gRow, blk, 0, stream>>>(
            buf2, (size_t)ns * 256, wtb + O_T3, 30720, biasp + OB_T3, 120,
            trajAllB, (size_t)N_TOK * 120, shtraj + (size_t)s0 * 120, 5, 256, 120);

        // score path: 128 -> 128 -> 64 -> 1 (reuses buf1/buf2)
        gemm_bf16<true,  true ><<<gRow, blk, 0, stream>>>(
            xbS, 0,            wtb + O_S1, 16384, biasp + OB_S1, 128,
            buf1, (size_t)ns * 128, nullptr, 6, 128, 128);
        gemm_bf16<true,  true ><<<gRow, blk, 0, stream>>>(
            buf1, (size_t)ns * 128, wtb + O_S2, 8192, biasp + OB_S2, 64,
            buf2, (size_t)ns * 64, nullptr, 6, 128, 64);
        score_l3<<<dim3(ns / 256, 6), blk, 0, stream>>>(
            buf2, (size_t)ns * 64, biasp + OW_S3, biasp + OB_S3,
            scoreAllB, N_TOK, shscore + s0);
    }

    // ---- combine ----
    combine_kernel<<<dim3((N_TOK * 120) / 256), blk, 0, stream>>>(
        out + OFF_TRAJALL, out + OFF_SCOREALL, shtraj, shscore,
        tp, ti, out + OFF_TRAJ, out + OFF_SCORE);
}